// Round 3
// baseline (3969.843 us; speedup 1.0000x reference)
//
#include <hip/hip_runtime.h>
#include <cstdint>

// CVFRLayer persistent-kernel version.
// x_{t+1} = (1-dt)x + dt*(nl(x) @ B) + sqrt(dt)*eps*(noise_t @ G^T)
// B = (A @ (I-P) + P)^T, P block-diagonal (16 blocks of 128, value pval)
//   => B^T operand [N][K] built from A's rows (prep_kernel).
// Fused per-step GEMM: C[m,n] = Y[m,:]@BTs[n,:] + Nb_t[m,:]@Gs[n,:] (K=4096 total),
// dt folded into BTs, sqrt(dt)*eps folded into Gs.
// ONE cooperative kernel runs all 100 steps; the 8 m-tile groups are fully
// independent recurrences, each synced by its own 32-block barrier.

typedef unsigned short ushort_t;
typedef __bf16 bf16x8 __attribute__((ext_vector_type(8)));
typedef float f32x4 __attribute__((ext_vector_type(4)));
typedef unsigned short u16x4 __attribute__((ext_vector_type(4)));
typedef unsigned short u16x8 __attribute__((ext_vector_type(8)));

#define SZ 2048
#define BATCH 512
#define NSTEPS 100

static constexpr float DT = 0.03f;
static constexpr float GAM = 0.125f;
static constexpr float PVAL = (float)(1.0 / (128.0 + 2.2627416997969522e-07));
static constexpr float CNOISE = 0.017320508075688773f;  // sqrt(dt)*eps

__device__ __forceinline__ unsigned short f2bf(float f) {
    unsigned int u = __builtin_bit_cast(unsigned int, f);
    return (unsigned short)((u + 0x7fffu + ((u >> 16) & 1u)) >> 16);
}
__device__ __forceinline__ void async16(const void* g, void* l) {
    __builtin_amdgcn_global_load_lds(
        (__attribute__((address_space(1))) void*)(uintptr_t)g,
        (__attribute__((address_space(3))) void*)(uint32_t)(uintptr_t)l,
        16, 0, 0);
}

// ---------- conv: noise f32 -> bf16 (whole trajectory) ----------
__global__ __launch_bounds__(256) void conv_kernel(const float* __restrict__ n,
                                                   ushort_t* __restrict__ nb) {
    const size_t i = ((size_t)blockIdx.x * 256 + threadIdx.x) * 4;
    f32x4 v = *(const f32x4*)(n + i);
    u16x4 o;
#pragma unroll
    for (int e = 0; e < 4; ++e) o[e] = f2bf(v[e]);
    *(u16x4*)(nb + i) = o;
}

// ---------- prep: BTs (dt-scaled B^T rows) and Gs (cnoise-scaled G rows), bf16 ----------
__global__ __launch_bounds__(256) void prep_kernel(const float* __restrict__ A,
                                                   const float* __restrict__ G,
                                                   ushort_t* __restrict__ BTs,
                                                   ushort_t* __restrict__ Gs) {
    const int n = blockIdx.x;
    const int t = threadIdx.x;
    __shared__ float s16[16];
    const float* arow = A + (size_t)n * SZ;
    f32x4 a0 = *(const f32x4*)(arow + t * 8);
    f32x4 a1 = *(const f32x4*)(arow + t * 8 + 4);
    float ps = a0[0] + a0[1] + a0[2] + a0[3] + a1[0] + a1[1] + a1[2] + a1[3];
#pragma unroll
    for (int m = 1; m < 16; m <<= 1) ps += __shfl_xor(ps, m, 64);
    if ((t & 15) == 0) s16[t >> 4] = ps * PVAL;
    __syncthreads();
    const int seg = t >> 4;
    const float s = s16[seg];
    const float diag = (seg == (n >> 7)) ? PVAL : 0.0f;
    float av[8] = {a0[0], a0[1], a0[2], a0[3], a1[0], a1[1], a1[2], a1[3]};
    u16x8 ov;
#pragma unroll
    for (int i = 0; i < 8; ++i) ov[i] = f2bf(DT * (av[i] - s + diag));
    *(u16x8*)&BTs[(size_t)n * SZ + t * 8] = ov;

    const float* grow = G + (size_t)n * SZ;
    f32x4 g0 = *(const f32x4*)(grow + t * 8);
    f32x4 g1 = *(const f32x4*)(grow + t * 8 + 4);
    float gv[8] = {g0[0], g0[1], g0[2], g0[3], g1[0], g1[1], g1[2], g1[3]};
    u16x8 og;
#pragma unroll
    for (int i = 0; i < 8; ++i) og[i] = f2bf(CNOISE * gv[i]);
    *(u16x8*)&Gs[(size_t)n * SZ + t * 8] = og;
}

// ---------- init: Y0 = bf16(nl(x)); zero the 8 group barriers ----------
__global__ __launch_bounds__(256) void init_kernel(const float* __restrict__ x,
                                                   ushort_t* __restrict__ Y0,
                                                   unsigned* __restrict__ bar) {
    const size_t i = ((size_t)blockIdx.x * 256 + threadIdx.x) * 4;
    f32x4 xv = *(const f32x4*)(x + i);
    u16x4 yv;
#pragma unroll
    for (int e = 0; e < 4; ++e) {
        float x2 = xv[e] * xv[e];
        yv[e] = f2bf(x2 / (GAM + x2));
    }
    *(u16x4*)(Y0 + i) = yv;
    if (blockIdx.x == 0) bar[threadIdx.x] = 0u;  // 256 u32 covers 8 groups * 32-u32 stride
}

// 32-block group barrier (blocks sharing one m-tile). Agent-scope fenced.
__device__ __forceinline__ void group_barrier(unsigned* cnt, unsigned* gen) {
    __syncthreads();  // compiler emits vmcnt(0) drain: block stores are in L2
    if (threadIdx.x == 0) {
        __threadfence();  // release: push to coherent point (wbL2)
        unsigned g = atomicAdd(gen, 0u);
        if (atomicAdd(cnt, 1u) == 31u) {
            atomicExch(cnt, 0u);
            __threadfence();
            atomicAdd(gen, 1u);
        } else {
            while (atomicAdd(gen, 0u) == g) __builtin_amdgcn_s_sleep(8);
        }
        __threadfence();  // acquire: invalidate stale L1/L2
    }
    __syncthreads();
}

// ---------- persistent step kernel: all 100 steps ----------
// 256 blocks x 512 threads, 128KB LDS -> exactly 1 block/CU, 2 waves/SIMD.
// Block (m,n) owns 64x64 output tile. 8 waves each own a K=512 slice of the
// fused K=4096 (waves 0-3: Y@BTs, waves 4-7: Nb_t@Gs), wave-private
// double-buffered LDS staging (16 chunks of k=32), no barriers in K-loop.
// x tile lives in registers for the whole run.
__global__ __launch_bounds__(512, 2) void persist_kernel(
    const float* __restrict__ x0,
    const ushort_t* __restrict__ BTs, const ushort_t* __restrict__ Gs,
    const ushort_t* __restrict__ Nb,
    ushort_t* __restrict__ Y0, ushort_t* __restrict__ Y1,
    float* __restrict__ xout, unsigned* __restrict__ bar) {
    extern __shared__ ushort_t smem[];  // 128KB
    const int tid = threadIdx.x;
    const int w = tid >> 6, l = tid & 63;
    const int id = blockIdx.x;
    const int nIdx = (id & 7) | (((id >> 3) & 3) << 3);  // same-n blocks -> same XCD
    const int mIdx = id >> 5;
    const int m0 = mIdx << 6, n0 = nIdx << 6;

    unsigned* cnt = bar + mIdx * 32;
    unsigned* gen = cnt + 1;

    // B operand base: constant across steps
    const char* Bg = (w < 4)
        ? ((const char*)BTs + (size_t)n0 * 4096 + w * 1024)
        : ((const char*)Gs + (size_t)n0 * 4096 + (w - 4) * 1024);
    char* waveLds = (char*)smem + w * 16384;  // 2 bufs x (A 4KB + B 4KB)

    // staging: slot s=i*64+l -> row=i*16+(l>>2), pos p=l&3, global chunk q=p^((row>>1)&3)
    const int goffL = (l >> 2) * 4096 + (((l & 3) ^ ((l >> 3) & 3)) << 4);
    const int loffL = l * 16;
    const int lr = l & 15, q8 = l >> 4;
    const int qpos = (q8 ^ ((lr >> 1) & 3)) << 4;

    // x registers: thread owns rows {m0+p*32+er}, cols n0+ec0..ec0+3
    const int er = tid >> 4;          // 0..31
    const int ec0 = (tid & 15) << 2;  // 0..60
    f32x4 xreg[2];
    xreg[0] = *(const f32x4*)(x0 + (size_t)(m0 + er) * SZ + n0 + ec0);
    xreg[1] = *(const f32x4*)(x0 + (size_t)(m0 + 32 + er) * SZ + n0 + ec0);

    for (int t = 0; t < NSTEPS; ++t) {
        const ushort_t* Yc = (t & 1) ? Y1 : Y0;
        ushort_t* Yn = (t & 1) ? Y0 : Y1;
        const char* Ag = (w < 4)
            ? ((const char*)Yc + (size_t)m0 * 4096 + w * 1024)
            : ((const char*)Nb + (size_t)t * 2097152 + (size_t)m0 * 4096 + (w - 4) * 1024);

        f32x4 acc[4][4] = {};

        auto stage = [&](int ci, int b) {
            const char* Ac = Ag + ci * 64;
            const char* Bc = Bg + ci * 64;
            char* dA = waveLds + b * 8192;
            char* dB = dA + 4096;
#pragma unroll
            for (int i = 0; i < 4; ++i) {
                async16(Ac + i * 65536 + goffL, dA + i * 1024 + loffL);
                async16(Bc + i * 65536 + goffL, dB + i * 1024 + loffL);
            }
        };
        auto compute = [&](int b) {
            const char* TA = waveLds + b * 8192;
            const char* TB = TA + 4096;
            bf16x8 af[4], bfv[4];
#pragma unroll
            for (int f = 0; f < 4; ++f) {
                af[f] = *(const bf16x8*)(TA + (f * 16 + lr) * 64 + qpos);
                bfv[f] = *(const bf16x8*)(TB + (f * 16 + lr) * 64 + qpos);
            }
#pragma unroll
            for (int fr = 0; fr < 4; ++fr)
#pragma unroll
                for (int fc = 0; fc < 4; ++fc)
                    acc[fr][fc] = __builtin_amdgcn_mfma_f32_16x16x32_bf16(
                        af[fr], bfv[fc], acc[fr][fc], 0, 0, 0);
        };

        stage(0, 0);
#pragma unroll 2
        for (int ci = 0; ci < 16; ++ci) {
            if (ci < 15) {
                stage(ci + 1, (ci + 1) & 1);
                asm volatile("s_waitcnt vmcnt(8)" ::: "memory");  // chunk ci drained
            } else {
                asm volatile("s_waitcnt vmcnt(0)" ::: "memory");
            }
            compute(ci & 1);
        }

        // 8-way K-split reduction (two phases of 32 rows), then x update in regs
        float* redF = (float*)smem;
#pragma unroll
        for (int p = 0; p < 2; ++p) {
            __syncthreads();
#pragma unroll
            for (int fl = 0; fl < 2; ++fl) {
                const int fr = p * 2 + fl;
                const int rl = fl * 16 + q8 * 4;
#pragma unroll
                for (int fc = 0; fc < 4; ++fc) {
                    const int c = fc * 16 + lr;
#pragma unroll
                    for (int reg = 0; reg < 4; ++reg)
                        redF[w * 2176 + (rl + reg) * 68 + c] = acc[p * 2 + fl == fr ? fr : fr][fc][reg];
                }
            }
            __syncthreads();
            {
                const int off = er * 68 + ec0;
                f32x4 s = *(const f32x4*)&redF[off];
#pragma unroll
                for (int ww = 1; ww < 8; ++ww)
                    s = s + *(const f32x4*)&redF[ww * 2176 + off];
                f32x4 xn = xreg[p] * (1.0f - DT) + s;
                xreg[p] = xn;
                const size_t gb = (size_t)(m0 + p * 32 + er) * SZ + n0 + ec0;
                if (t < NSTEPS - 1) {
                    u16x4 yv;
#pragma unroll
                    for (int e = 0; e < 4; ++e) {
                        float x2 = xn[e] * xn[e];
                        yv[e] = f2bf(x2 / (GAM + x2));
                    }
                    *(u16x4*)(Yn + gb) = yv;
                } else {
                    *(f32x4*)(xout + gb) = xn;
                }
            }
        }

        if (t < NSTEPS - 1) group_barrier(cnt, gen);
    }
}

extern "C" void kernel_launch(void* const* d_in, const int* in_sizes, int n_in,
                              void* d_out, int out_size, void* d_ws, size_t ws_size,
                              hipStream_t stream) {
    const float* x = (const float*)d_in[0];
    const float* A = (const float*)d_in[1];
    const float* G = (const float*)d_in[2];
    const float* noise = (const float*)d_in[3];
    float* out = (float*)d_out;
    char* ws = (char*)d_ws;

    unsigned* bar = (unsigned*)(ws);                          // 1KB (8 groups * 128B)
    ushort_t* Y0 = (ushort_t*)(ws + ((size_t)1 << 20));       // 2MB
    ushort_t* Y1 = (ushort_t*)(ws + ((size_t)3 << 20));       // 2MB
    ushort_t* BTs = (ushort_t*)(ws + ((size_t)5 << 20));      // 8MB
    ushort_t* Gsc = (ushort_t*)(ws + ((size_t)13 << 20));     // 8MB
    ushort_t* Nb = (ushort_t*)(ws + ((size_t)21 << 20));      // 200MB (ends ~221MB)

    (void)hipFuncSetAttribute((const void*)persist_kernel,
                              hipFuncAttributeMaxDynamicSharedMemorySize, 131072);

    conv_kernel<<<dim3(102400), dim3(256), 0, stream>>>(noise, Nb);
    prep_kernel<<<dim3(SZ), dim3(256), 0, stream>>>(A, G, BTs, Gsc);
    init_kernel<<<dim3(1024), dim3(256), 0, stream>>>(x, Y0, bar);

    void* args[] = {(void*)&x, (void*)&BTs, (void*)&Gsc, (void*)&Nb,
                    (void*)&Y0, (void*)&Y1, (void*)&out, (void*)&bar};
    (void)hipLaunchCooperativeKernel((const void*)persist_kernel, dim3(256), dim3(512),
                                     args, 131072, stream);
}